// Round 1
// baseline (2387.692 us; speedup 1.0000x reference)
//
#include <hip/hip_runtime.h>
#include <math.h>

#define BB 128
#define T2 2050
#define TT 2049
#define HH 64
#define GG 448   // 7*H
#define KK 100
#define NE 103   // K+3

__device__ __forceinline__ float softplusf(float x) {
    // log1p(exp(x)) stable
    return fmaxf(x, 0.f) + log1pf(expf(-fabsf(x)));
}

__device__ __forceinline__ float sigmoidf(float x) {
    return 1.f / (1.f + expf(-x));
}

// pre_emb[e][t] = sum_k in_emb[e][k] * Wx[k][t] + bias[t]   (103 x 448)
__global__ void pre_emb_kernel(const float* __restrict__ in_emb,
                               const float* __restrict__ Wx,
                               const float* __restrict__ bias,
                               float* __restrict__ pre_emb) {
    int e = blockIdx.x;     // 0..102
    int t = threadIdx.x;    // 0..447
    float acc = bias[t];
#pragma unroll
    for (int k = 0; k < HH; ++k)
        acc = fmaf(in_emb[e * HH + k], Wx[k * GG + t], acc);
    pre_emb[e * GG + t] = acc;
}

__device__ __forceinline__ float dot64(const float* __restrict__ hs,
                                       const float* __restrict__ w) {
    const float4* h4 = (const float4*)hs;
    float a0 = 0.f, a1 = 0.f, a2 = 0.f, a3 = 0.f;
#pragma unroll
    for (int k4 = 0; k4 < HH / 4; ++k4) {
        float4 hv = h4[k4];
        a0 = fmaf(hv.x, w[4 * k4 + 0], a0);
        a1 = fmaf(hv.y, w[4 * k4 + 1], a1);
        a2 = fmaf(hv.z, w[4 * k4 + 2], a2);
        a3 = fmaf(hv.w, w[4 * k4 + 3], a3);
    }
    return (a0 + a1) + (a2 + a3);
}

// One block per batch row. Threads 0..447: gate matmul (thread t holds Wh[:,t]
// in regs). Threads 448..547: logits+softplus for the PREVIOUS step's h
// (thread holds out_emb row in regs) — overlaps the epilogue with the
// recurrence critical path. Threads <64 (wave 0) also own the c/cb/h update.
__launch_bounds__(576, 1)
__global__ void scan_kernel(const int* __restrict__ event,
                            const float* __restrict__ dtime,
                            const float* __restrict__ pre_emb,
                            const float* __restrict__ Wh,
                            const float* __restrict__ out_emb,
                            float* __restrict__ out) {
    const int b   = blockIdx.x;
    const int tid = threadIdx.x;
    const int w   = tid >> 6;          // wave index 0..8

    __shared__ __align__(16) float h_s[HH];
    __shared__ float gbuf[GG];

    const bool is_mat = tid < GG;
    const int  r      = tid - GG;      // 0..127 for waves 7-8
    const bool is_log = (tid >= GG) && (r < KK);

    float wcol[HH];
    if (is_mat) {
#pragma unroll
        for (int k = 0; k < HH; ++k) wcol[k] = Wh[k * GG + tid];
    } else if (is_log) {
#pragma unroll
        for (int k = 0; k < HH; ++k) wcol[k] = out_emb[r * HH + k];
    }

    if (tid < HH) h_s[tid] = 0.f;
    float c = 0.f, cb = 0.f;           // live only in threads < 64

    const int*   ev_row = event + b * T2;
    const float* dt_row = dtime + b * T2;
    float*       out_row = out + (size_t)b * TT * KK;

    __syncthreads();

    for (int t = 0; t < TT; ++t) {
        if (is_mat) {
            const int ev = ev_row[t];
            float acc = pre_emb[ev * GG + tid] + dot64(h_s, wcol);
            float val;
            if (w == 2)      val = tanhf(acc);       // z
            else if (w == 6) val = softplusf(acc);   // delta
            else             val = sigmoidf(acc);    // i,f,o,ib,fb
            gbuf[tid] = val;
        } else if (is_log && t > 0) {
            // h_s currently holds h_{t-1}
            float lg = dot64(h_s, wcol);
            out_row[(size_t)(t - 1) * KK + r] = softplusf(lg);
        }
        __syncthreads();
        if (tid < HH) {
            const float gi  = gbuf[tid];
            const float gf  = gbuf[HH + tid];
            const float gz  = gbuf[2 * HH + tid];
            const float go  = gbuf[3 * HH + tid];
            const float gib = gbuf[4 * HH + tid];
            const float gfb = gbuf[5 * HH + tid];
            const float gd  = gbuf[6 * HH + tid];
            const float dt  = dt_row[t + 1];
            const float ci  = fmaf(gf, c, gi * gz);
            const float cbi = fmaf(gfb, cb, gib * gz);
            const float cn  = fmaf(ci - cbi, expf(-gd * dt), cbi);
            const float h   = go * tanhf(cn);
            c  = cn;
            cb = cbi;
            h_s[tid] = h;
        }
        __syncthreads();
    }

    // tail: logits for the final step (h_s holds h_{T-1})
    if (is_log) {
        float lg = dot64(h_s, wcol);
        out_row[(size_t)(TT - 1) * KK + r] = softplusf(lg);
    }
}

extern "C" void kernel_launch(void* const* d_in, const int* in_sizes, int n_in,
                              void* d_out, int out_size, void* d_ws, size_t ws_size,
                              hipStream_t stream) {
    const int*   event  = (const int*)d_in[0];
    const float* dtime  = (const float*)d_in[1];
    const float* in_emb = (const float*)d_in[2];
    const float* Wx     = (const float*)d_in[3];
    const float* Wh     = (const float*)d_in[4];
    const float* bias   = (const float*)d_in[5];
    const float* oe     = (const float*)d_in[6];
    float*       out    = (float*)d_out;

    float* pre_emb = (float*)d_ws;  // 103*448*4 = 184,576 bytes

    pre_emb_kernel<<<NE, GG, 0, stream>>>(in_emb, Wx, bias, pre_emb);
    scan_kernel<<<BB, 576, 0, stream>>>(event, dtime, pre_emb, Wh, oe, out);
}

// Round 2
// 1627.684 us; speedup vs baseline: 1.4669x; 1.4669x over previous
//
#include <hip/hip_runtime.h>
#include <math.h>

#define BB 128
#define T2 2050
#define TT 2049
#define HH 64
#define GG 448   // 7*H
#define KK 100
#define NE 103   // K+3
#define WIN 32   // output buffering window (steps)

#define LOG2E 1.44269504088896340736f
#define LN2   0.69314718055994530942f

// ---- fast transcendentals (native v_exp_f32 / v_log_f32 / v_rcp_f32) ----
__device__ __forceinline__ float frcp(float x) { return __builtin_amdgcn_rcpf(x); }

__device__ __forceinline__ float sigmoid_fast(float x) {
    // 1/(1+2^(-x*log2e))
    return frcp(1.f + exp2f(-x * LOG2E));
}
__device__ __forceinline__ float tanh_fast(float x) {
    // 1 - 2/(1+e^{2x}); inf-safe at both ends
    float e = exp2f(x * (2.f * LOG2E));
    return 1.f - 2.f * frcp(1.f + e);
}
__device__ __forceinline__ float softplus_fast(float x) {
    // max(x,0) + ln2*log2(1+2^(-|x|*log2e))
    float t = exp2f(-fabsf(x) * LOG2E);
    return fmaxf(x, 0.f) + LN2 * log2f(1.f + t);
}
__device__ __forceinline__ float expn_fast(float x) {   // e^x
    return exp2f(x * LOG2E);
}

// pre_emb[e][t] = sum_k in_emb[e][k] * Wx[k][t] + bias[t]   (103 x 448)
__global__ void pre_emb_kernel(const float* __restrict__ in_emb,
                               const float* __restrict__ Wx,
                               const float* __restrict__ bias,
                               float* __restrict__ pre_emb) {
    int e = blockIdx.x;
    int t = threadIdx.x;
    float acc = bias[t];
#pragma unroll
    for (int k = 0; k < HH; ++k)
        acc = fmaf(in_emb[e * HH + k], Wx[k * GG + t], acc);
    pre_emb[e * GG + t] = acc;
}

__device__ __forceinline__ float dot64(const float* __restrict__ hs,
                                       const float* __restrict__ w) {
    const float4* h4 = (const float4*)hs;
    float a0 = 0.f, a1 = 0.f, a2 = 0.f, a3 = 0.f;
#pragma unroll
    for (int k4 = 0; k4 < HH / 4; ++k4) {
        float4 hv = h4[k4];
        a0 = fmaf(hv.x, w[4 * k4 + 0], a0);
        a1 = fmaf(hv.y, w[4 * k4 + 1], a1);
        a2 = fmaf(hv.z, w[4 * k4 + 2], a2);
        a3 = fmaf(hv.w, w[4 * k4 + 3], a3);
    }
    return (a0 + a1) + (a2 + a3);
}

// One block per batch row; 9 waves.
//  - threads 0..447 (waves 0-6): gate matmul, thread t holds Wh[:,t] in regs.
//    ev/pre_emb row/dt are prefetched one step ahead (private loads are NOT
//    drained at s_barrier — only stores/LDS are — so latency fully overlaps).
//  - threads 448..575 (waves 7-8): logits+softplus for h_{t-1} into an LDS
//    ring buffer (WIN steps); flushed to global once per WIN steps so the
//    vmcnt(0)-before-barrier store drain leaves the per-step critical path.
//  - threads <64 additionally own the c/cb/h state update (stage 2).
__launch_bounds__(576, 1)
__global__ void scan_kernel(const int* __restrict__ event,
                            const float* __restrict__ dtime,
                            const float* __restrict__ pre_emb,
                            const float* __restrict__ Wh,
                            const float* __restrict__ out_emb,
                            float* __restrict__ out) {
    const int b   = blockIdx.x;
    const int tid = threadIdx.x;
    const int w   = tid >> 6;

    __shared__ __align__(16) float h_s[HH];
    __shared__ float gbuf[GG];
    __shared__ float obuf[WIN * KK];   // 12.8 KB output ring

    const bool is_mat = tid < GG;
    const int  r      = tid - GG;          // 0..127 for waves 7-8
    const bool is_log = (tid >= GG) && (r < KK);

    float wcol[HH];
    if (is_mat) {
#pragma unroll
        for (int k = 0; k < HH; ++k) wcol[k] = Wh[k * GG + tid];
    } else if (is_log) {
#pragma unroll
        for (int k = 0; k < HH; ++k) wcol[k] = out_emb[r * HH + k];
    }

    if (tid < HH) h_s[tid] = 0.f;
    float c = 0.f, cb = 0.f;

    const int*   ev_row  = event + b * T2;
    const float* dt_row  = dtime + b * T2;
    float*       out_row = out + (size_t)b * TT * KK;

    // prefetch pipeline state (gate threads)
    float pe_cur = 0.f;
    int   evn    = 0;
    if (is_mat) {
        int ev0 = ev_row[0];
        pe_cur  = pre_emb[ev0 * GG + tid];
        evn     = ev_row[1];
    }
    float dtc = 0.f;
    if (tid < HH) dtc = dt_row[1];

    __syncthreads();

    for (int t = 0; t < TT; ++t) {
        float pe_nxt = 0.f, dtn = 0.f;
        const int tn = (t + 2 < T2) ? (t + 2) : (T2 - 1);
        if (is_mat) {
            // issue next-step prefetches first so latency overlaps this step
            pe_nxt = pre_emb[evn * GG + tid];
            evn    = ev_row[tn];
            if (tid < HH) dtn = dt_row[tn];

            float acc = pe_cur + dot64(h_s, wcol);
            float val;
            if (w == 2)      val = tanh_fast(acc);       // z
            else if (w == 6) val = softplus_fast(acc);   // delta
            else             val = sigmoid_fast(acc);    // i,f,o,ib,fb
            gbuf[tid] = val;
        } else {
            // flush completed output window (same waves own obuf: no race)
            if (t >= WIN + 1 && ((t - 1) & (WIN - 1)) == 0) {
                const int base = t - 1 - WIN;
                const int i = tid - GG;   // 0..127
#pragma unroll
                for (int j = 0; j < (WIN * KK) / 128; ++j) {
                    const int idx = j * 128 + i;
                    out_row[(size_t)base * KK + idx] = obuf[idx];
                }
            }
            if (is_log && t >= 1) {
                // h_s holds h_{t-1}
                float lg = dot64(h_s, wcol);
                obuf[((t - 1) & (WIN - 1)) * KK + r] = softplus_fast(lg);
            }
        }
        __syncthreads();
        if (tid < HH) {
            const float gi  = gbuf[tid];
            const float gf  = gbuf[HH + tid];
            const float gz  = gbuf[2 * HH + tid];
            const float go  = gbuf[3 * HH + tid];
            const float gib = gbuf[4 * HH + tid];
            const float gfb = gbuf[5 * HH + tid];
            const float gd  = gbuf[6 * HH + tid];
            const float ci  = fmaf(gf, c, gi * gz);
            const float cbi = fmaf(gfb, cb, gib * gz);
            const float cn  = fmaf(ci - cbi, expn_fast(-gd * dtc), cbi);
            const float h   = go * tanh_fast(cn);
            c   = cn;
            cb  = cbi;
            dtc = dtn;
            h_s[tid] = h;
        }
        if (is_mat) pe_cur = pe_nxt;
        __syncthreads();
    }

    // tail: flush last full window (steps 2016..2047) + final step direct
    if (tid >= GG) {
        const int base = ((TT - 1) / WIN) * WIN - 0;  // 2048 - but last unflushed full window starts at 2016
        const int fbase = TT - 1 - WIN;               // 2016
        const int i = tid - GG;
#pragma unroll
        for (int j = 0; j < (WIN * KK) / 128; ++j) {
            const int idx = j * 128 + i;
            out_row[(size_t)fbase * KK + idx] = obuf[idx];
        }
        (void)base;
        if (r < KK) {
            float lg = dot64(h_s, wcol);   // h_s = h_{T-1}
            out_row[(size_t)(TT - 1) * KK + r] = softplus_fast(lg);
        }
    }
}

extern "C" void kernel_launch(void* const* d_in, const int* in_sizes, int n_in,
                              void* d_out, int out_size, void* d_ws, size_t ws_size,
                              hipStream_t stream) {
    const int*   event  = (const int*)d_in[0];
    const float* dtime  = (const float*)d_in[1];
    const float* in_emb = (const float*)d_in[2];
    const float* Wx     = (const float*)d_in[3];
    const float* Wh     = (const float*)d_in[4];
    const float* bias   = (const float*)d_in[5];
    const float* oe     = (const float*)d_in[6];
    float*       out    = (float*)d_out;

    float* pre_emb = (float*)d_ws;  // 103*448*4 = 184,576 bytes

    pre_emb_kernel<<<NE, GG, 0, stream>>>(in_emb, Wx, bias, pre_emb);
    scan_kernel<<<BB, 576, 0, stream>>>(event, dtime, pre_emb, Wh, oe, out);
}